// Round 1
// baseline (239.434 us; speedup 1.0000x reference)
//
#include <hip/hip_runtime.h>

#define BB 8
#define NN 2048
#define FF 128
#define ROWS 32
#define MT 64

// ---------------------------------------------------------------------------
// kernel 1: h = feat @ W + b  (row-major, f32), plus e_src = h@a[:128],
//           e_dst = h@a[128:]. 8 rows per 256-thread block.
// ---------------------------------------------------------------------------
__global__ __launch_bounds__(256) void k_h(
    const float* __restrict__ feat, const float* __restrict__ W,
    const float* __restrict__ bias, const float* __restrict__ a,
    float* __restrict__ h, float* __restrict__ esrc, float* __restrict__ edst)
{
    __shared__ float fsh[8][FF];
    __shared__ float red[2][2][8];
    const int t = threadIdx.x;
    const long row0 = (long)blockIdx.x * 8;

    // stage 8 feature rows (1024 floats = 256 float4)
    ((float4*)&fsh[0][0])[t] = ((const float4*)(feat + row0 * FF))[t];
    __syncthreads();

    const int o = t & 127;        // output column
    const int half = t >> 7;      // rows half*4 .. half*4+3
    float acc[4] = {0.f, 0.f, 0.f, 0.f};
    #pragma unroll 4
    for (int k = 0; k < FF; ++k) {
        const float w = W[k * FF + o];
        #pragma unroll
        for (int r = 0; r < 4; ++r)
            acc[r] = fmaf(fsh[half * 4 + r][k], w, acc[r]);
    }
    const float bo = bias[o];
    const float as = a[o];
    const float ad = a[FF + o];
    float ps[4], pd[4];
    #pragma unroll
    for (int r = 0; r < 4; ++r) {
        acc[r] += bo;
        h[(row0 + half * 4 + r) * FF + o] = acc[r];
        ps[r] = acc[r] * as;
        pd[r] = acc[r] * ad;
    }
    // reduce over the 128 threads (2 waves) of this half
    #pragma unroll
    for (int r = 0; r < 4; ++r) {
        #pragma unroll
        for (int off = 32; off > 0; off >>= 1) {
            ps[r] += __shfl_down(ps[r], off, 64);
            pd[r] += __shfl_down(pd[r], off, 64);
        }
    }
    const int wv = (t >> 6) & 1;  // which wave within the half
    if ((t & 63) == 0) {
        #pragma unroll
        for (int r = 0; r < 4; ++r) {
            red[half][wv][r]     = ps[r];
            red[half][wv][4 + r] = pd[r];
        }
    }
    __syncthreads();
    if (t < 16) {
        const int hh = t >> 3, idx = t & 7;
        const float v = red[hh][0][idx] + red[hh][1][idx];
        const long row = row0 + hh * 4 + (idx & 3);
        if (idx < 4) esrc[row] = v;
        else         edst[row] = v;
    }
}

// ---------------------------------------------------------------------------
// kernel 2: gmax[b] = max_m e_dst[b][m]  (upper-bound softmax shift source)
// ---------------------------------------------------------------------------
__global__ __launch_bounds__(256) void k_gmax(
    const float* __restrict__ edst, float* __restrict__ gmax)
{
    const int b = blockIdx.x;
    const int t = threadIdx.x;
    float m = -1e30f;
    for (int i = t; i < NN; i += 256) m = fmaxf(m, edst[b * NN + i]);
    #pragma unroll
    for (int off = 32; off > 0; off >>= 1) m = fmaxf(m, __shfl_down(m, off, 64));
    __shared__ float sm[4];
    if ((t & 63) == 0) sm[t >> 6] = m;
    __syncthreads();
    if (t == 0) gmax[b] = fmaxf(fmaxf(sm[0], sm[1]), fmaxf(sm[2], sm[3]));
}

// ---------------------------------------------------------------------------
// kernel 3: per 32-row tile: p = adj ? exp(leaky(es+ed) - M) : 0 (single pass,
// M = leaky(es + gmax) >= rowmax by monotonicity), then out = (p @ h) / sum(p).
// ---------------------------------------------------------------------------
__global__ __launch_bounds__(256) void k_attn(
    const int* __restrict__ adj, const float* __restrict__ mask,
    const float* __restrict__ h, const float* __restrict__ esrc,
    const float* __restrict__ edst, const float* __restrict__ gmax,
    float* __restrict__ out)
{
    __shared__ float p_sh[ROWS][MT + 1];  // [row][m] — phase-A writes coalesced
    __shared__ float h_sh[MT][FF];
    __shared__ float es_sh[ROWS];
    __shared__ float M_sh[ROWS];
    __shared__ float psum_sh[ROWS];

    const int t = threadIdx.x;
    const int b = blockIdx.x >> 6;            // NN/ROWS = 64 tiles per batch
    const int n0 = (blockIdx.x & 63) * ROWS;

    if (t < ROWS) {
        const float es = esrc[b * NN + n0 + t];
        es_sh[t] = es;
        const float e = es + gmax[b];
        M_sh[t] = (e >= 0.f) ? e : 0.01f * e;
    }

    // phase A mapping: thread = (g, mloc), rows g+4k for k=0..7
    const int mloc = t & 63;
    const int g = t >> 6;
    float psum_part[8];
    #pragma unroll
    for (int k = 0; k < 8; ++k) psum_part[k] = 0.f;

    // phase B mapping: 4 rows x 4 output cols per thread
    const int rg = t >> 5;
    const int o0 = (t & 31) * 4;
    float acc[4][4];
    #pragma unroll
    for (int r = 0; r < 4; ++r)
        #pragma unroll
        for (int c = 0; c < 4; ++c) acc[r][c] = 0.f;

    const long hbase = (long)b * NN * FF;
    const long adjrow = (long)b * NN * NN + (long)n0 * NN;

    for (int m0 = 0; m0 < NN; m0 += MT) {
        __syncthreads();  // previous phase B done; also publishes es_sh/M_sh
        // stage h tile (MT x 128 f32 = 32 KB)
        {
            const float4* hs = (const float4*)(h + hbase + (long)m0 * FF);
            float4* hd = (float4*)&h_sh[0][0];
            #pragma unroll
            for (int i = 0; i < (MT * FF / 4) / 256; ++i)
                hd[t + 256 * i] = hs[t + 256 * i];
        }
        // compute p tile
        const float ed = edst[b * NN + m0 + mloc];
        #pragma unroll
        for (int k = 0; k < 8; ++k) {
            const int r = g + 4 * k;
            const int av = adj[adjrow + (long)r * NN + m0 + mloc];
            float e = es_sh[r] + ed;
            e = (e >= 0.f) ? e : 0.01f * e;
            const float p = (av > 0) ? __expf(e - M_sh[r]) : 0.f;
            p_sh[r][mloc] = p;
            psum_part[k] += p;
        }
        __syncthreads();
        // accumulate out += p @ h_tile
        #pragma unroll 2
        for (int m = 0; m < MT; ++m) {
            const float4 hv = *(const float4*)&h_sh[m][o0];
            #pragma unroll
            for (int r = 0; r < 4; ++r) {
                const float pv = p_sh[rg * 4 + r][m];
                acc[r][0] = fmaf(pv, hv.x, acc[r][0]);
                acc[r][1] = fmaf(pv, hv.y, acc[r][1]);
                acc[r][2] = fmaf(pv, hv.z, acc[r][2]);
                acc[r][3] = fmaf(pv, hv.w, acc[r][3]);
            }
        }
    }

    // reduce psum per row (rows g+4k live in wave g: lanes t = g*64..g*64+63)
    #pragma unroll
    for (int k = 0; k < 8; ++k) {
        float v = psum_part[k];
        #pragma unroll
        for (int off = 32; off > 0; off >>= 1) v += __shfl_down(v, off, 64);
        if ((t & 63) == 0) psum_sh[g + 4 * k] = v;
    }
    __syncthreads();

    #pragma unroll
    for (int r = 0; r < 4; ++r) {
        const int row = rg * 4 + r;
        const float s = mask[b * NN + n0 + row] / psum_sh[row];
        float4 v;
        v.x = acc[r][0] * s;
        v.y = acc[r][1] * s;
        v.z = acc[r][2] * s;
        v.w = acc[r][3] * s;
        *(float4*)&out[hbase + (long)(n0 + row) * FF + o0] = v;
    }
}

// ---------------------------------------------------------------------------
extern "C" void kernel_launch(void* const* d_in, const int* in_sizes, int n_in,
                              void* d_out, int out_size, void* d_ws, size_t ws_size,
                              hipStream_t stream)
{
    const float* feat = (const float*)d_in[0];
    const int*   adj  = (const int*)d_in[1];
    const float* mask = (const float*)d_in[2];
    const float* W    = (const float*)d_in[3];
    const float* bias = (const float*)d_in[4];
    const float* a    = (const float*)d_in[5];
    float* out = (float*)d_out;

    // workspace layout (f32): h[8*2048*128] | esrc[16384] | edst[16384] | gmax[8]
    float* h    = (float*)d_ws;
    float* esrc = h + (size_t)BB * NN * FF;
    float* edst = esrc + BB * NN;
    float* gmax = edst + BB * NN;

    k_h   <<<BB * NN / 8, 256, 0, stream>>>(feat, W, bias, a, h, esrc, edst);
    k_gmax<<<BB,          256, 0, stream>>>(edst, gmax);
    k_attn<<<BB * (NN / ROWS), 256, 0, stream>>>(adj, mask, h, esrc, edst, gmax, out);
}

// Round 2
// 129.837 us; speedup vs baseline: 1.8441x; 1.8441x over previous
//
#include <hip/hip_runtime.h>

#define BB 8
#define NN 2048
#define FF 128
#define ROWS 32
#define MT 128

typedef short bh8 __attribute__((ext_vector_type(8)));
typedef float fl4 __attribute__((ext_vector_type(4)));
typedef unsigned short u16;

__device__ __forceinline__ u16 f2bf(float x) {
    unsigned u = __float_as_uint(x);
    return (u16)((u + 0x7FFFu + ((u >> 16) & 1u)) >> 16);
}

// ---------------------------------------------------------------------------
// kernel 1: h = feat @ W + b; store h as bf16 TRANSPOSED htg[b][o][n];
// also e_src = h@a[:128], e_dst = h@a[128:]. 8 rows per 256-thread block.
// ---------------------------------------------------------------------------
__global__ __launch_bounds__(256) void k_h(
    const float* __restrict__ feat, const float* __restrict__ W,
    const float* __restrict__ bias, const float* __restrict__ a,
    u16* __restrict__ htg, float* __restrict__ esrc, float* __restrict__ edst)
{
    __shared__ float fsh[8][FF];
    __shared__ float red[2][2][8];
    const int t = threadIdx.x;
    const long row0 = (long)blockIdx.x * 8;

    ((float4*)&fsh[0][0])[t] = ((const float4*)(feat + row0 * FF))[t];
    __syncthreads();

    const int o = t & 127;
    const int half = t >> 7;
    float acc[4] = {0.f, 0.f, 0.f, 0.f};
    #pragma unroll 4
    for (int k = 0; k < FF; ++k) {
        const float w = W[k * FF + o];
        #pragma unroll
        for (int r = 0; r < 4; ++r)
            acc[r] = fmaf(fsh[half * 4 + r][k], w, acc[r]);
    }
    const float bo = bias[o];
    const float as = a[o];
    const float ad = a[FF + o];
    float ps[4], pd[4];
    #pragma unroll
    for (int r = 0; r < 4; ++r) {
        acc[r] += bo;
        ps[r] = acc[r] * as;
        pd[r] = acc[r] * ad;
    }
    // bf16 transposed store: htg[(b*128 + o)*2048 + nloc + r]
    {
        const int bI = (int)(row0 >> 11);
        const int nloc = (int)(row0 & 2047) + half * 4;
        ushort4 hv;
        hv.x = f2bf(acc[0]); hv.y = f2bf(acc[1]);
        hv.z = f2bf(acc[2]); hv.w = f2bf(acc[3]);
        *(ushort4*)&htg[((long)bI * FF + o) * NN + nloc] = hv;
    }
    #pragma unroll
    for (int r = 0; r < 4; ++r) {
        #pragma unroll
        for (int off = 32; off > 0; off >>= 1) {
            ps[r] += __shfl_down(ps[r], off, 64);
            pd[r] += __shfl_down(pd[r], off, 64);
        }
    }
    const int wv = (t >> 6) & 1;
    if ((t & 63) == 0) {
        #pragma unroll
        for (int r = 0; r < 4; ++r) {
            red[half][wv][r]     = ps[r];
            red[half][wv][4 + r] = pd[r];
        }
    }
    __syncthreads();
    if (t < 16) {
        const int hh = t >> 3, idx = t & 7;
        const float v = red[hh][0][idx] + red[hh][1][idx];
        const long row = row0 + hh * 4 + (idx & 3);
        if (idx < 4) esrc[row] = v;
        else         edst[row] = v;
    }
}

// ---------------------------------------------------------------------------
// kernel 2: gmax[b] = max_m e_dst[b][m]
// ---------------------------------------------------------------------------
__global__ __launch_bounds__(256) void k_gmax(
    const float* __restrict__ edst, float* __restrict__ gmax)
{
    const int b = blockIdx.x;
    const int t = threadIdx.x;
    float m = -1e30f;
    for (int i = t; i < NN; i += 256) m = fmaxf(m, edst[b * NN + i]);
    #pragma unroll
    for (int off = 32; off > 0; off >>= 1) m = fmaxf(m, __shfl_down(m, off, 64));
    __shared__ float sm[4];
    if ((t & 63) == 0) sm[t >> 6] = m;
    __syncthreads();
    if (t == 0) gmax[b] = fmaxf(fmaxf(sm[0], sm[1]), fmaxf(sm[2], sm[3]));
}

// ---------------------------------------------------------------------------
// kernel 3: per 32-row tile: P = adj ? exp(leaky(es+ed) - M) : 0 (bf16 in LDS),
// then out = (P @ H) * mask / rowsum(P) via mfma_f32_16x16x32_bf16.
// B-fragments read directly from global htg (no reuse within block -> no LDS).
// Wave w: rows 16*(w&1)..+15, cols 64*(w>>1)..+63 (4 col tiles of 16).
// ---------------------------------------------------------------------------
__global__ __launch_bounds__(256) void k_attn(
    const int* __restrict__ adj, const float* __restrict__ mask,
    const u16* __restrict__ htg, const float* __restrict__ esrc,
    const float* __restrict__ edst, const float* __restrict__ gmax,
    float* __restrict__ out)
{
    __shared__ u16 p_sh[ROWS][MT + 8];
    __shared__ float es_sh[ROWS];
    __shared__ float M_sh[ROWS];
    __shared__ float psum_sh[ROWS];

    const int t = threadIdx.x;
    const int b = blockIdx.x & 7;               // batch -> XCD affinity
    const int n0 = (blockIdx.x >> 3) * ROWS;    // 64 tiles per batch

    if (t < ROWS) {
        const float es = esrc[b * NN + n0 + t];
        es_sh[t] = es;
        const float e = es + gmax[b];
        M_sh[t] = (e >= 0.f) ? e : 0.01f * e;   // leaky(es+gmax) >= rowmax
    }

    // phase A mapping: half-wave lane31 covers 4 ints of m; rg*4..+3 rows
    const int lane31 = t & 31;
    const int rg = t >> 5;
    const long adjbase = (long)b * NN * NN + (long)(n0 + rg * 4) * NN;
    float psum_part[4] = {0.f, 0.f, 0.f, 0.f};

    // MFMA mapping
    const int w = t >> 6, lane = t & 63;
    const int rt = w & 1;
    const int c0 = (w >> 1) * 64;
    const int lr = lane & 15, g = lane >> 4;
    const u16* hB = htg + (long)b * FF * NN;

    fl4 acc[4];
    #pragma unroll
    for (int ct = 0; ct < 4; ++ct) acc[ct] = (fl4){0.f, 0.f, 0.f, 0.f};

    for (int m0 = 0; m0 < NN; m0 += MT) {
        __syncthreads();   // prev MFMA done reading p_sh (also publishes es/M)
        const float4 ed4 = *(const float4*)(edst + b * NN + m0 + lane31 * 4);
        const float edv[4] = {ed4.x, ed4.y, ed4.z, ed4.w};
        #pragma unroll
        for (int r = 0; r < 4; ++r) {
            const int row = rg * 4 + r;
            const float es = es_sh[row];
            const float Mv = M_sh[row];
            const int4 av = *(const int4*)(adj + adjbase + (long)r * NN + m0 + lane31 * 4);
            const int avi[4] = {av.x, av.y, av.z, av.w};
            u16 pb[4];
            #pragma unroll
            for (int j = 0; j < 4; ++j) {
                float e = es + edv[j];
                e = (e >= 0.f) ? e : 0.01f * e;
                const float p = (avi[j] > 0) ? __expf(e - Mv) : 0.f;
                const u16 ub = f2bf(p);
                pb[j] = ub;
                // accumulate the ROUNDED value -> numerator/denominator consistent
                psum_part[r] += __uint_as_float((unsigned)ub << 16);
            }
            *(ushort4*)&p_sh[row][lane31 * 4] = make_ushort4(pb[0], pb[1], pb[2], pb[3]);
        }
        __syncthreads();   // p tile ready

        #pragma unroll
        for (int kc = 0; kc < 4; ++kc) {
            const bh8 afrag = *(const bh8*)&p_sh[lr + 16 * rt][kc * 32 + g * 8];
            #pragma unroll
            for (int ct = 0; ct < 4; ++ct) {
                const bh8 bfrag = *(const bh8*)(hB + (long)(c0 + ct * 16 + lr) * NN
                                                + m0 + kc * 32 + g * 8);
                acc[ct] = __builtin_amdgcn_mfma_f32_16x16x32_bf16(afrag, bfrag, acc[ct], 0, 0, 0);
            }
        }
    }

    // psum: reduce within each 32-lane group
    #pragma unroll
    for (int r = 0; r < 4; ++r) {
        float v = psum_part[r];
        #pragma unroll
        for (int off = 16; off > 0; off >>= 1) v += __shfl_down(v, off, 32);
        if (lane31 == 0) psum_sh[rg * 4 + r] = v;
    }
    __syncthreads();

    // epilogue: C/D layout col=lane&15, row=(lane>>4)*4+reg  [m89/m91]
    const long obase = ((long)b * NN + n0) * FF;
    #pragma unroll
    for (int reg = 0; reg < 4; ++reg) {
        const int rowin = 16 * rt + g * 4 + reg;
        const float s = mask[b * NN + n0 + rowin] / psum_sh[rowin];
        #pragma unroll
        for (int ct = 0; ct < 4; ++ct) {
            out[obase + (long)rowin * FF + c0 + ct * 16 + lr] = acc[ct][reg] * s;
        }
    }
}

// ---------------------------------------------------------------------------
extern "C" void kernel_launch(void* const* d_in, const int* in_sizes, int n_in,
                              void* d_out, int out_size, void* d_ws, size_t ws_size,
                              hipStream_t stream)
{
    const float* feat = (const float*)d_in[0];
    const int*   adj  = (const int*)d_in[1];
    const float* mask = (const float*)d_in[2];
    const float* W    = (const float*)d_in[3];
    const float* bias = (const float*)d_in[4];
    const float* a    = (const float*)d_in[5];
    float* out = (float*)d_out;

    // ws layout: htg bf16 [8][128][2048] (4MB) | esrc f32 | edst f32 | gmax f32
    u16*   htg  = (u16*)d_ws;
    float* esrc = (float*)(htg + (size_t)BB * FF * NN);
    float* edst = esrc + BB * NN;
    float* gmax = edst + BB * NN;

    k_h   <<<BB * NN / 8, 256, 0, stream>>>(feat, W, bias, a, htg, esrc, edst);
    k_gmax<<<BB,          256, 0, stream>>>(edst, gmax);
    k_attn<<<BB * (NN / ROWS), 256, 0, stream>>>(adj, mask, htg, esrc, edst, gmax, out);
}

// Round 3
// 92.557 us; speedup vs baseline: 2.5869x; 1.4028x over previous
//
#include <hip/hip_runtime.h>

#define BB 8
#define NN 2048
#define FF 128
#define ROWS 32
#define MT 128
#define PPAD 8

typedef short bh8 __attribute__((ext_vector_type(8)));
typedef float fl4 __attribute__((ext_vector_type(4)));
typedef unsigned short u16;

__device__ __forceinline__ u16 f2bf(float x) {
    unsigned u = __float_as_uint(x);
    return (u16)((u + 0x7FFFu + ((u >> 16) & 1u)) >> 16);
}

// ---------------------------------------------------------------------------
// kernel 1: h = feat @ W + b; store h as bf16 TRANSPOSED htg[b][o][n];
// also e_src = h@a[:128], e_dst = h@a[128:]. 8 rows per 256-thread block.
// ---------------------------------------------------------------------------
__global__ __launch_bounds__(256) void k_h(
    const float* __restrict__ feat, const float* __restrict__ W,
    const float* __restrict__ bias, const float* __restrict__ a,
    u16* __restrict__ htg, float* __restrict__ esrc, float* __restrict__ edst)
{
    __shared__ float fsh[8][FF];
    __shared__ float red[2][2][8];
    const int t = threadIdx.x;
    const long row0 = (long)blockIdx.x * 8;

    ((float4*)&fsh[0][0])[t] = ((const float4*)(feat + row0 * FF))[t];
    __syncthreads();

    const int o = t & 127;
    const int half = t >> 7;
    float acc[4] = {0.f, 0.f, 0.f, 0.f};
    #pragma unroll 4
    for (int k = 0; k < FF; ++k) {
        const float w = W[k * FF + o];
        #pragma unroll
        for (int r = 0; r < 4; ++r)
            acc[r] = fmaf(fsh[half * 4 + r][k], w, acc[r]);
    }
    const float bo = bias[o];
    const float as = a[o];
    const float ad = a[FF + o];
    float ps[4], pd[4];
    #pragma unroll
    for (int r = 0; r < 4; ++r) {
        acc[r] += bo;
        ps[r] = acc[r] * as;
        pd[r] = acc[r] * ad;
    }
    {
        const int bI = (int)(row0 >> 11);
        const int nloc = (int)(row0 & 2047) + half * 4;
        ushort4 hv;
        hv.x = f2bf(acc[0]); hv.y = f2bf(acc[1]);
        hv.z = f2bf(acc[2]); hv.w = f2bf(acc[3]);
        *(ushort4*)&htg[((long)bI * FF + o) * NN + nloc] = hv;
    }
    #pragma unroll
    for (int r = 0; r < 4; ++r) {
        #pragma unroll
        for (int off = 32; off > 0; off >>= 1) {
            ps[r] += __shfl_down(ps[r], off, 64);
            pd[r] += __shfl_down(pd[r], off, 64);
        }
    }
    const int wv = (t >> 6) & 1;
    if ((t & 63) == 0) {
        #pragma unroll
        for (int r = 0; r < 4; ++r) {
            red[half][wv][r]     = ps[r];
            red[half][wv][4 + r] = pd[r];
        }
    }
    __syncthreads();
    if (t < 16) {
        const int hh = t >> 3, idx = t & 7;
        const float v = red[hh][0][idx] + red[hh][1][idx];
        const long row = row0 + hh * 4 + (idx & 3);
        if (idx < 4) esrc[row] = v;
        else         edst[row] = v;
    }
}

// ---------------------------------------------------------------------------
// kernel 2: gmax[b] = max_m e_dst[b][m]
// ---------------------------------------------------------------------------
__global__ __launch_bounds__(256) void k_gmax(
    const float* __restrict__ edst, float* __restrict__ gmax)
{
    const int b = blockIdx.x;
    const int t = threadIdx.x;
    float m = -1e30f;
    for (int i = t; i < NN; i += 256) m = fmaxf(m, edst[b * NN + i]);
    #pragma unroll
    for (int off = 32; off > 0; off >>= 1) m = fmaxf(m, __shfl_down(m, off, 64));
    __shared__ float sm[4];
    if ((t & 63) == 0) sm[t >> 6] = m;
    __syncthreads();
    if (t == 0) gmax[b] = fmaxf(fmaxf(sm[0], sm[1]), fmaxf(sm[2], sm[3]));
}

// ---------------------------------------------------------------------------
// kernel 3: 512 threads (8 waves = 2 row-halves x 4 col-quarters).
// Per m-tile: phase A builds bf16 P tile (double-buffered LDS), MFMA consumes.
// One raw barrier per tile (lgkm drain only, vmcnt stays in flight).
// adj/edst prefetched one tile ahead; B-frags from global (L2) issued at loop top.
// ---------------------------------------------------------------------------
__global__ __launch_bounds__(512, 4) void k_attn(
    const int* __restrict__ adj, const float* __restrict__ mask,
    const u16* __restrict__ htg, const float* __restrict__ esrc,
    const float* __restrict__ edst, const float* __restrict__ gmax,
    float* __restrict__ out)
{
    __shared__ u16 p_sh[2][ROWS][MT + PPAD];
    __shared__ float psum_sh[ROWS];

    const int t = threadIdx.x;
    const int b = blockIdx.x & 7;               // batch -> XCD affinity
    const int n0 = (blockIdx.x >> 3) * ROWS;

    // phase-A mapping: thread covers rows {pr0, pr0+1}, m lane31*4..+3
    const int lane31 = t & 31;
    const int pr0 = (t >> 5) * 2;
    const long adjbase = (long)b * NN * NN + (long)(n0 + pr0) * NN;

    const float es0 = esrc[b * NN + n0 + pr0];
    const float es1 = esrc[b * NN + n0 + pr0 + 1];
    const float gm = gmax[b];
    const float t0 = es0 + gm; const float M0 = (t0 >= 0.f) ? t0 : 0.01f * t0;
    const float t1 = es1 + gm; const float M1 = (t1 >= 0.f) ? t1 : 0.01f * t1;

    // MFMA mapping
    const int w = t >> 6, lane = t & 63;
    const int rt = w & 1;                       // row half (16 rows)
    const int c0 = (w >> 1) * 32;               // col quarter (2 tiles of 16)
    const int lr = lane & 15, g = lane >> 4;
    const u16* hB = htg + (long)b * FF * NN;

    fl4 acc0 = (fl4){0.f, 0.f, 0.f, 0.f};
    fl4 acc1 = (fl4){0.f, 0.f, 0.f, 0.f};
    float psum0 = 0.f, psum1 = 0.f;

    // prefetch tile 0 adj / edst
    int4 adjv0 = *(const int4*)(adj + adjbase + lane31 * 4);
    int4 adjv1 = *(const int4*)(adj + adjbase + NN + lane31 * 4);
    float4 edv = *(const float4*)(edst + b * NN + lane31 * 4);

    int cur = 0;
    for (int m0 = 0; m0 < NN; m0 += MT) {
        // issue B-fragment loads for this tile (independent of P)
        bh8 bfrag[4][2];
        #pragma unroll
        for (int kc = 0; kc < 4; ++kc)
            #pragma unroll
            for (int ct = 0; ct < 2; ++ct)
                bfrag[kc][ct] = *(const bh8*)(hB + (long)(c0 + ct * 16 + lr) * NN
                                              + m0 + kc * 32 + g * 8);

        // phase A: P for rows pr0, pr0+1 from prefetched regs
        {
            const float edf[4] = {edv.x, edv.y, edv.z, edv.w};
            const int a0[4] = {adjv0.x, adjv0.y, adjv0.z, adjv0.w};
            const int a1[4] = {adjv1.x, adjv1.y, adjv1.z, adjv1.w};
            u16 pb0[4], pb1[4];
            #pragma unroll
            for (int j = 0; j < 4; ++j) {
                float x0 = es0 + edf[j]; x0 = (x0 >= 0.f) ? x0 : 0.01f * x0;
                float x1 = es1 + edf[j]; x1 = (x1 >= 0.f) ? x1 : 0.01f * x1;
                const float p0 = (a0[j] > 0) ? __expf(x0 - M0) : 0.f;
                const float p1 = (a1[j] > 0) ? __expf(x1 - M1) : 0.f;
                const u16 u0 = f2bf(p0), u1 = f2bf(p1);
                pb0[j] = u0; pb1[j] = u1;
                // accumulate ROUNDED values -> numerator/denominator consistent
                psum0 += __uint_as_float((unsigned)u0 << 16);
                psum1 += __uint_as_float((unsigned)u1 << 16);
            }
            *(ushort4*)&p_sh[cur][pr0][lane31 * 4]     = make_ushort4(pb0[0], pb0[1], pb0[2], pb0[3]);
            *(ushort4*)&p_sh[cur][pr0 + 1][lane31 * 4] = make_ushort4(pb1[0], pb1[1], pb1[2], pb1[3]);
        }

        // prefetch next tile's adj / edst (flies across the barrier)
        {
            const int mn = (m0 + MT < NN) ? (m0 + MT) : m0;
            adjv0 = *(const int4*)(adj + adjbase + mn + lane31 * 4);
            adjv1 = *(const int4*)(adj + adjbase + NN + mn + lane31 * 4);
            edv   = *(const float4*)(edst + b * NN + mn + lane31 * 4);
        }

        // publish P tile: drain LDS writes only; vmcnt stays outstanding
        asm volatile("s_waitcnt lgkmcnt(0)" ::: "memory");
        __builtin_amdgcn_s_barrier();
        asm volatile("" ::: "memory");

        // A-frags from LDS + MFMA
        #pragma unroll
        for (int kc = 0; kc < 4; ++kc) {
            const bh8 afrag = *(const bh8*)&p_sh[cur][16 * rt + lr][kc * 32 + g * 8];
            acc0 = __builtin_amdgcn_mfma_f32_16x16x32_bf16(afrag, bfrag[kc][0], acc0, 0, 0, 0);
            acc1 = __builtin_amdgcn_mfma_f32_16x16x32_bf16(afrag, bfrag[kc][1], acc1, 0, 0, 0);
        }
        cur ^= 1;
    }

    // psum: reduce within each 32-lane group (rows pr0, pr0+1)
    #pragma unroll
    for (int off = 16; off > 0; off >>= 1) {
        psum0 += __shfl_down(psum0, off, 32);
        psum1 += __shfl_down(psum1, off, 32);
    }
    if (lane31 == 0) { psum_sh[pr0] = psum0; psum_sh[pr0 + 1] = psum1; }
    __syncthreads();

    // epilogue: C/D layout col=lane&15, row=(lane>>4)*4+reg  [m89/m91]
    const long obase = ((long)b * NN + n0) * FF;
    #pragma unroll
    for (int reg = 0; reg < 4; ++reg) {
        const int rowin = 16 * rt + g * 4 + reg;
        const float s = mask[b * NN + n0 + rowin] / psum_sh[rowin];
        out[obase + (long)rowin * FF + c0 + lr]      = acc0[reg] * s;
        out[obase + (long)rowin * FF + c0 + 16 + lr] = acc1[reg] * s;
    }
}

// ---------------------------------------------------------------------------
extern "C" void kernel_launch(void* const* d_in, const int* in_sizes, int n_in,
                              void* d_out, int out_size, void* d_ws, size_t ws_size,
                              hipStream_t stream)
{
    const float* feat = (const float*)d_in[0];
    const int*   adj  = (const int*)d_in[1];
    const float* mask = (const float*)d_in[2];
    const float* W    = (const float*)d_in[3];
    const float* bias = (const float*)d_in[4];
    const float* a    = (const float*)d_in[5];
    float* out = (float*)d_out;

    // ws layout: htg bf16 [8][128][2048] (4MB) | esrc f32 | edst f32 | gmax f32
    u16*   htg  = (u16*)d_ws;
    float* esrc = (float*)(htg + (size_t)BB * FF * NN);
    float* edst = esrc + BB * NN;
    float* gmax = edst + BB * NN;

    k_h   <<<BB * NN / 8, 256, 0, stream>>>(feat, W, bias, a, htg, esrc, edst);
    k_gmax<<<BB,          256, 0, stream>>>(edst, gmax);
    k_attn<<<BB * (NN / ROWS), 512, 0, stream>>>(adj, mask, htg, esrc, edst, gmax, out);
}